// Round 5
// baseline (416.687 us; speedup 1.0000x reference)
//
#include <hip/hip_runtime.h>
#include <hip/hip_bf16.h>

#define N_NODES 100000
#define N_EDGES 1600000
#define N_FEAT  16
#define HIDDEN  128
#define N_GRAPHS 512
#define NB_SCAN 391   // ceil(N_NODES/256)

typedef unsigned short ushort_t;

// ---------------- degree count + rank capture ----------------

__global__ void k_deg(const int* __restrict__ dst, int* __restrict__ cnt,
                      int* __restrict__ rank) {
    int e = blockIdx.x * blockDim.x + threadIdx.x;
    if (e < N_EDGES) rank[e] = atomicAdd(&cnt[dst[e]], 1);
}

// ---------------- exclusive scan over cnt -> rowptr (3 phases) ----------------

__device__ __forceinline__ int wave_incl_scan(int v) {
    int lane = threadIdx.x & 63;
    #pragma unroll
    for (int off = 1; off < 64; off <<= 1) {
        int u = __shfl_up(v, off, 64);
        if (lane >= off) v += u;
    }
    return v;
}

__global__ __launch_bounds__(256) void k_bsum(const int* __restrict__ cnt,
                                              int* __restrict__ bsum) {
    int i = blockIdx.x * 256 + threadIdx.x;
    int v = (i < N_NODES) ? cnt[i] : 0;
    #pragma unroll
    for (int off = 32; off; off >>= 1) v += __shfl_down(v, off, 64);
    __shared__ int ws[4];
    int wave = threadIdx.x >> 6, lane = threadIdx.x & 63;
    if (lane == 0) ws[wave] = v;
    __syncthreads();
    if (threadIdx.x == 0) bsum[blockIdx.x] = ws[0] + ws[1] + ws[2] + ws[3];
}

__global__ __launch_bounds__(512) void k_scanb(const int* __restrict__ bsum,
                                               int* __restrict__ boff) {
    int tid = threadIdx.x;
    int v = (tid < NB_SCAN) ? bsum[tid] : 0;
    int incl = wave_incl_scan(v);
    __shared__ int ws[8];
    int wave = tid >> 6, lane = tid & 63;
    if (lane == 63) ws[wave] = incl;
    __syncthreads();
    int add = 0;
    for (int w = 0; w < wave; ++w) add += ws[w];
    if (tid < NB_SCAN) boff[tid] = add + incl - v;
}

__global__ __launch_bounds__(256) void k_scanf(const int* __restrict__ cnt,
                                               const int* __restrict__ boff,
                                               int* __restrict__ rowptr,
                                               float* __restrict__ dinv) {
    int tid = threadIdx.x;
    int i = blockIdx.x * 256 + tid;
    int v = (i < N_NODES) ? cnt[i] : 0;
    int incl = wave_incl_scan(v);
    __shared__ int ws[4];
    int wave = tid >> 6, lane = tid & 63;
    if (lane == 63) ws[wave] = incl;
    __syncthreads();
    int add = boff[blockIdx.x];
    for (int w = 0; w < wave; ++w) add += ws[w];
    int excl = add + incl - v;
    if (i < N_NODES) {
        rowptr[i] = excl;
        dinv[i] = rsqrtf((float)v + 1.0f);
    }
    if (i == N_NODES - 1) rowptr[N_NODES] = excl + v;
}

// ---------------- bucket edges by dst (atomic-free) ----------------

__global__ void k_bucket(const int* __restrict__ src, const int* __restrict__ dst,
                         const int* __restrict__ rank, const int* __restrict__ rowptr,
                         int* __restrict__ esrc) {
    int e = blockIdx.x * blockDim.x + threadIdx.x;
    if (e < N_EDGES)
        esrc[rowptr[dst[e]] + rank[e]] = src[e];
}

// ---------------- layer-1 aggregation in 16-dim ----------------

__global__ __launch_bounds__(256) void k_agg1(const int* __restrict__ rowptr,
                                              const int* __restrict__ esrc,
                                              const float* __restrict__ dinv,
                                              const float* __restrict__ x,
                                              float* __restrict__ agg16) {
    int tid = threadIdx.x;
    int wave = tid >> 6;
    int lane = tid & 63;
    int e = lane >> 4;       // edge group 0..3
    int f = lane & 15;       // feature
    int node = blockIdx.x * 4 + wave;
    int beg = rowptr[node], end = rowptr[node + 1];
    float dd = dinv[node];

    float acc = 0.0f;
    int j = beg + e;
    for (; j + 4 < end; j += 8) {
        int sA = esrc[j];     float wA = dinv[sA] * dd;
        int sB = esrc[j + 4]; float wB = dinv[sB] * dd;
        float vA = x[sA * N_FEAT + f];
        float vB = x[sB * N_FEAT + f];
        acc += vA * wA + vB * wB;
    }
    if (j < end) {
        int s = esrc[j];
        acc += x[s * N_FEAT + f] * (dinv[s] * dd);
    }
    acc += __shfl_xor(acc, 16, 64);
    acc += __shfl_xor(acc, 32, 64);
    if (e == 0)
        agg16[node * N_FEAT + f] = acc + x[node * N_FEAT + f] * dd * dd;
}

// ---------------- mm1: h1 = bf16(relu(agg16 @ W1 + b1)) ----------------

#define MM1_NODES 16
__global__ __launch_bounds__(256) void k_mm1b(const float* __restrict__ a,
                                              const float* __restrict__ W1,
                                              const float* __restrict__ b1,
                                              __hip_bfloat16* __restrict__ out) {
    __shared__ float sw[N_FEAT][HIDDEN];
    __shared__ float sx[MM1_NODES][N_FEAT + 1];
    int tid = threadIdx.x;
    int n0 = blockIdx.x * MM1_NODES;

    for (int i = tid; i < N_FEAT * HIDDEN; i += 256)
        sw[i >> 7][i & 127] = W1[i];
    if (tid < MM1_NODES * N_FEAT) {
        int n = tid >> 4, k = tid & 15;
        sx[n][k] = a[(n0 + n) * N_FEAT + k];
    }
    __syncthreads();

    int f = tid & 127, half = tid >> 7;
    float bias = b1[f];
    float acc[8] = {0,0,0,0,0,0,0,0};
    #pragma unroll
    for (int k = 0; k < N_FEAT; ++k) {
        float w = sw[k][f];
        #pragma unroll
        for (int i = 0; i < 8; ++i)
            acc[i] += sx[half * 8 + i][k] * w;
    }
    #pragma unroll
    for (int i = 0; i < 8; ++i)
        out[(n0 + half * 8 + i) * HIDDEN + f] =
            __float2bfloat16(fmaxf(acc[i] + bias, 0.0f));
}

// ---------------- layer-2 aggregation, bf16 gather ----------------

__device__ __forceinline__ float bf_lo(unsigned u) {
    union { unsigned i; float f; } c; c.i = u << 16; return c.f;
}
__device__ __forceinline__ float bf_hi(unsigned u) {
    union { unsigned i; float f; } c; c.i = u & 0xffff0000u; return c.f;
}

__global__ __launch_bounds__(256) void k_agg2(const int* __restrict__ rowptr,
                                              const int* __restrict__ esrc,
                                              const float* __restrict__ dinv,
                                              const ushort_t* __restrict__ h1,
                                              float* __restrict__ agg2) {
    int tid = threadIdx.x;
    int sub = tid >> 5;      // 0..7 node within block
    int l32 = tid & 31;      // 8-byte lane within node row
    int node = blockIdx.x * 8 + sub;
    const uint2* h = (const uint2*)h1;   // row = 32 x uint2 (4 bf16 each)
    int beg = rowptr[node], end = rowptr[node + 1];
    float dd = dinv[node];
    uint2 sv = h[node * 32 + l32];
    float dd2 = dd * dd;
    float a0 = bf_lo(sv.x) * dd2, a1 = bf_hi(sv.x) * dd2;
    float a2 = bf_lo(sv.y) * dd2, a3 = bf_hi(sv.y) * dd2;

    int j = beg;
    for (; j + 4 <= end; j += 4) {
        int s0 = esrc[j], s1 = esrc[j + 1], s2 = esrc[j + 2], s3 = esrc[j + 3];
        float w0 = dinv[s0] * dd, w1 = dinv[s1] * dd,
              w2 = dinv[s2] * dd, w3 = dinv[s3] * dd;
        uint2 v0 = h[s0 * 32 + l32];
        uint2 v1 = h[s1 * 32 + l32];
        uint2 v2 = h[s2 * 32 + l32];
        uint2 v3 = h[s3 * 32 + l32];
        a0 += bf_lo(v0.x) * w0 + bf_lo(v1.x) * w1 + bf_lo(v2.x) * w2 + bf_lo(v3.x) * w3;
        a1 += bf_hi(v0.x) * w0 + bf_hi(v1.x) * w1 + bf_hi(v2.x) * w2 + bf_hi(v3.x) * w3;
        a2 += bf_lo(v0.y) * w0 + bf_lo(v1.y) * w1 + bf_lo(v2.y) * w2 + bf_lo(v3.y) * w3;
        a3 += bf_hi(v0.y) * w0 + bf_hi(v1.y) * w1 + bf_hi(v2.y) * w2 + bf_hi(v3.y) * w3;
    }
    for (; j < end; ++j) {
        int s = esrc[j];
        float w = dinv[s] * dd;
        uint2 v = h[s * 32 + l32];
        a0 += bf_lo(v.x) * w; a1 += bf_hi(v.x) * w;
        a2 += bf_lo(v.y) * w; a3 += bf_hi(v.y) * w;
    }
    float4 r = {a0, a1, a2, a3};
    ((float4*)agg2)[node * 32 + l32] = r;
}

// ---------------- mm2 fused head: snode[n] = dot(relu(agg2[n]@W2 + b2), Wl) ----------------
// node-major LDS tile (no transpose): staging = contiguous float4 copy;
// a-reads are wave-broadcast (conflict-free); w-reads stride-16 b128.

__global__ __launch_bounds__(256) void k_mm2s(const float* __restrict__ h,
                                              const float* __restrict__ W2,
                                              const float* __restrict__ b2,
                                              const float* __restrict__ Wl,
                                              float* __restrict__ snode) {
    __shared__ float sh[64][132];      // node-major, pad to 132 (33.8 KB)
    __shared__ float sw[32][HIDDEN];   // W2 k-tile (16 KB)
    int tid = threadIdx.x;
    int n0 = blockIdx.x * 64;

    {
        const float4* hv = (const float4*)h;
        #pragma unroll
        for (int j = 0; j < 8; ++j) {
            int q = tid + 256 * j;   // float4 idx 0..2047
            int n = q >> 5;          // node 0..63
            int kq = q & 31;         // float4 within row
            int gn = n0 + n;
            float4 v = {0.f, 0.f, 0.f, 0.f};
            if (gn < N_NODES) v = hv[gn * 32 + kq];
            *(float4*)(&sh[n][kq * 4]) = v;
        }
    }

    int tcol = tid & 31;
    int trow = tid >> 5;
    float acc[8][4] = {};

    for (int kt = 0; kt < 4; ++kt) {
        __syncthreads();
        {
            const float4* wv = (const float4*)(W2 + kt * 32 * HIDDEN);
            float4* swv = (float4*)(&sw[0][0]);
            #pragma unroll
            for (int j = 0; j < 4; ++j)
                swv[tid + 256 * j] = wv[tid + 256 * j];
        }
        __syncthreads();
        #pragma unroll
        for (int k4 = 0; k4 < 8; ++k4) {
            int kl = k4 * 4;              // k within tile
            int kg = kt * 32 + kl;        // global k
            float4 w0 = *(const float4*)(&sw[kl][tcol * 4]);
            float4 w1 = *(const float4*)(&sw[kl + 1][tcol * 4]);
            float4 w2 = *(const float4*)(&sw[kl + 2][tcol * 4]);
            float4 w3 = *(const float4*)(&sw[kl + 3][tcol * 4]);
            #pragma unroll
            for (int i = 0; i < 8; ++i) {
                float4 a = *(const float4*)(&sh[trow * 8 + i][kg]);
                acc[i][0] += a.x * w0.x + a.y * w1.x + a.z * w2.x + a.w * w3.x;
                acc[i][1] += a.x * w0.y + a.y * w1.y + a.z * w2.y + a.w * w3.y;
                acc[i][2] += a.x * w0.z + a.y * w1.z + a.z * w2.z + a.w * w3.z;
                acc[i][3] += a.x * w0.w + a.y * w1.w + a.z * w2.w + a.w * w3.w;
            }
        }
    }

    float4 bv = *(const float4*)(&b2[tcol * 4]);
    float4 wlv = *(const float4*)(&Wl[tcol * 4]);
    float bb[4] = {bv.x, bv.y, bv.z, bv.w};
    float wl[4] = {wlv.x, wlv.y, wlv.z, wlv.w};
    #pragma unroll
    for (int i = 0; i < 8; ++i) {
        float part = 0.0f;
        #pragma unroll
        for (int c = 0; c < 4; ++c)
            part += fmaxf(acc[i][c] + bb[c], 0.0f) * wl[c];
        #pragma unroll
        for (int off = 16; off; off >>= 1)
            part += __shfl_down(part, off, 32);
        int gn = n0 + trow * 8 + i;
        if (tcol == 0 && gn < N_NODES) snode[gn] = part;
    }
}

// ---------------- pooling: out[g] = mean(snode over graph g) + bl ----------------

__global__ __launch_bounds__(256) void k_pool(const float* __restrict__ snode,
                                              const int* __restrict__ batch,
                                              const float* __restrict__ bl,
                                              float* __restrict__ out) {
    int g = blockIdx.x;
    int tid = threadIdx.x;
    __shared__ float sred[4];

    int lo = 0, hi = N_NODES;
    while (lo < hi) { int mid = (lo + hi) >> 1; if (batch[mid] < g) lo = mid + 1; else hi = mid; }
    int start = lo;
    hi = N_NODES;
    while (lo < hi) { int mid = (lo + hi) >> 1; if (batch[mid] < g + 1) lo = mid + 1; else hi = mid; }
    int end = lo;

    float acc = 0.0f;
    for (int n = start + tid; n < end; n += 256) acc += snode[n];

    #pragma unroll
    for (int off = 32; off; off >>= 1) acc += __shfl_down(acc, off, 64);
    int wave = tid >> 6, lane = tid & 63;
    if (lane == 0) sred[wave] = acc;
    __syncthreads();
    if (tid == 0) {
        float s = sred[0] + sred[1] + sred[2] + sred[3];
        float cnt = (float)(end - start);
        out[g] = s / fmaxf(cnt, 1.0f) + bl[0];
    }
}

// ---------------- launch ----------------

extern "C" void kernel_launch(void* const* d_in, const int* in_sizes, int n_in,
                              void* d_out, int out_size, void* d_ws, size_t ws_size,
                              hipStream_t stream) {
    const float* x    = (const float*)d_in[0];
    const int*   src  = (const int*)d_in[1];
    const int*   dst  = src + N_EDGES;
    const int*   batch= (const int*)d_in[2];
    const float* W1   = (const float*)d_in[3];
    const float* b1   = (const float*)d_in[4];
    const float* W2   = (const float*)d_in[5];
    const float* b2   = (const float*)d_in[6];
    const float* Wl   = (const float*)d_in[7];
    const float* bl   = (const float*)d_in[8];
    float* out = (float*)d_out;

    const size_t NH = (size_t)N_NODES * HIDDEN;

    __hip_bfloat16* h1 = (__hip_bfloat16*)d_ws;       // NH bf16 (25.6 MB)
    float* agg2  = (float*)((char*)d_ws + NH * 2);    // NH fp32
    float* agg16 = agg2;                               // aliases (dead before agg2)
    float* dinv  = agg2 + NH;                          // N_NODES
    float* snode = dinv + N_NODES;                     // N_NODES
    int*   cnt    = (int*)(snode + N_NODES);           // N_NODES
    int*   rowptr = cnt + N_NODES;                     // N_NODES+1
    int*   rank   = rowptr + N_NODES + 1;              // N_EDGES
    int*   bsum   = rank + N_EDGES;                    // NB_SCAN
    int*   boff   = bsum + NB_SCAN;                    // NB_SCAN
    int*   esrc   = boff + NB_SCAN;                    // N_EDGES

    // CSR build
    hipMemsetAsync(cnt, 0, N_NODES * sizeof(int), stream);
    k_deg<<<(N_EDGES + 255) / 256, 256, 0, stream>>>(dst, cnt, rank);
    k_bsum<<<NB_SCAN, 256, 0, stream>>>(cnt, bsum);
    k_scanb<<<1, 512, 0, stream>>>(bsum, boff);
    k_scanf<<<NB_SCAN, 256, 0, stream>>>(cnt, boff, rowptr, dinv);
    k_bucket<<<(N_EDGES + 255) / 256, 256, 0, stream>>>(src, dst, rank, rowptr, esrc);

    // layer 1: aggregate in 16-dim, then matmul -> bf16 h1
    k_agg1<<<N_NODES / 4, 256, 0, stream>>>(rowptr, esrc, dinv, x, agg16);
    k_mm1b<<<N_NODES / MM1_NODES, 256, 0, stream>>>(agg16, W1, b1, h1);

    // layer 2: bf16 gather aggregate, fused mm2 + head dot
    k_agg2<<<N_NODES / 8, 256, 0, stream>>>(rowptr, esrc, dinv, (const ushort_t*)h1, agg2);
    k_mm2s<<<(N_NODES + 63) / 64, 256, 0, stream>>>(agg2, W2, b2, Wl, snode);

    // pool + bias
    k_pool<<<N_GRAPHS, 256, 0, stream>>>(snode, batch, bl, out);
}

// Round 6
// 323.505 us; speedup vs baseline: 1.2880x; 1.2880x over previous
//
#include <hip/hip_runtime.h>
#include <hip/hip_bf16.h>

#define N_NODES 100000
#define N_EDGES 1600000
#define N_FEAT  16
#define HIDDEN  128
#define N_GRAPHS 512
#define NB_SCAN 391   // ceil(N_NODES/256)

typedef unsigned short ushort_t;
typedef short v8s __attribute__((ext_vector_type(8)));   // 8 bf16 (4 VGPRs)
typedef float v4f __attribute__((ext_vector_type(4)));   // MFMA accumulator

__device__ __forceinline__ ushort_t f2bf(float f) {
    __hip_bfloat16 b = __float2bfloat16(f);
    return *(ushort_t*)&b;
}

// ---------------- degree count + rank capture ----------------

__global__ void k_deg(const int* __restrict__ dst, int* __restrict__ cnt,
                      int* __restrict__ rank) {
    int e = blockIdx.x * blockDim.x + threadIdx.x;
    if (e < N_EDGES) rank[e] = atomicAdd(&cnt[dst[e]], 1);
}

// ---------------- exclusive scan over cnt -> rowptr (3 phases) ----------------

__device__ __forceinline__ int wave_incl_scan(int v) {
    int lane = threadIdx.x & 63;
    #pragma unroll
    for (int off = 1; off < 64; off <<= 1) {
        int u = __shfl_up(v, off, 64);
        if (lane >= off) v += u;
    }
    return v;
}

__global__ __launch_bounds__(256) void k_bsum(const int* __restrict__ cnt,
                                              int* __restrict__ bsum) {
    int i = blockIdx.x * 256 + threadIdx.x;
    int v = (i < N_NODES) ? cnt[i] : 0;
    #pragma unroll
    for (int off = 32; off; off >>= 1) v += __shfl_down(v, off, 64);
    __shared__ int ws[4];
    int wave = threadIdx.x >> 6, lane = threadIdx.x & 63;
    if (lane == 0) ws[wave] = v;
    __syncthreads();
    if (threadIdx.x == 0) bsum[blockIdx.x] = ws[0] + ws[1] + ws[2] + ws[3];
}

__global__ __launch_bounds__(512) void k_scanb(const int* __restrict__ bsum,
                                               int* __restrict__ boff) {
    int tid = threadIdx.x;
    int v = (tid < NB_SCAN) ? bsum[tid] : 0;
    int incl = wave_incl_scan(v);
    __shared__ int ws[8];
    int wave = tid >> 6, lane = tid & 63;
    if (lane == 63) ws[wave] = incl;
    __syncthreads();
    int add = 0;
    for (int w = 0; w < wave; ++w) add += ws[w];
    if (tid < NB_SCAN) boff[tid] = add + incl - v;
}

__global__ __launch_bounds__(256) void k_scanf(const int* __restrict__ cnt,
                                               const int* __restrict__ boff,
                                               int* __restrict__ rowptr,
                                               float* __restrict__ dinv) {
    int tid = threadIdx.x;
    int i = blockIdx.x * 256 + tid;
    int v = (i < N_NODES) ? cnt[i] : 0;
    int incl = wave_incl_scan(v);
    __shared__ int ws[4];
    int wave = tid >> 6, lane = tid & 63;
    if (lane == 63) ws[wave] = incl;
    __syncthreads();
    int add = boff[blockIdx.x];
    for (int w = 0; w < wave; ++w) add += ws[w];
    int excl = add + incl - v;
    if (i < N_NODES) {
        rowptr[i] = excl;
        dinv[i] = rsqrtf((float)v + 1.0f);
    }
    if (i == N_NODES - 1) rowptr[N_NODES] = excl + v;
}

// ---------------- bucket edges by dst (atomic-free) ----------------

__global__ void k_bucket(const int* __restrict__ src, const int* __restrict__ dst,
                         const int* __restrict__ rank, const int* __restrict__ rowptr,
                         int* __restrict__ esrc) {
    int e = blockIdx.x * blockDim.x + threadIdx.x;
    if (e < N_EDGES)
        esrc[rowptr[dst[e]] + rank[e]] = src[e];
}

// ---------------- layer-1 aggregation in 16-dim ----------------

__global__ __launch_bounds__(256) void k_agg1(const int* __restrict__ rowptr,
                                              const int* __restrict__ esrc,
                                              const float* __restrict__ dinv,
                                              const float* __restrict__ x,
                                              float* __restrict__ agg16) {
    int tid = threadIdx.x;
    int wave = tid >> 6;
    int lane = tid & 63;
    int e = lane >> 4;       // edge group 0..3
    int f = lane & 15;       // feature
    int node = blockIdx.x * 4 + wave;
    int beg = rowptr[node], end = rowptr[node + 1];
    float dd = dinv[node];

    float acc = 0.0f;
    int j = beg + e;
    for (; j + 4 < end; j += 8) {
        int sA = esrc[j];     float wA = dinv[sA] * dd;
        int sB = esrc[j + 4]; float wB = dinv[sB] * dd;
        float vA = x[sA * N_FEAT + f];
        float vB = x[sB * N_FEAT + f];
        acc += vA * wA + vB * wB;
    }
    if (j < end) {
        int s = esrc[j];
        acc += x[s * N_FEAT + f] * (dinv[s] * dd);
    }
    acc += __shfl_xor(acc, 16, 64);
    acc += __shfl_xor(acc, 32, 64);
    if (e == 0)
        agg16[node * N_FEAT + f] = acc + x[node * N_FEAT + f] * dd * dd;
}

// ---------------- mm1: h1 = bf16(relu(agg16 @ W1 + b1)) ----------------

#define MM1_NODES 16
__global__ __launch_bounds__(256) void k_mm1b(const float* __restrict__ a,
                                              const float* __restrict__ W1,
                                              const float* __restrict__ b1,
                                              __hip_bfloat16* __restrict__ out) {
    __shared__ float sw[N_FEAT][HIDDEN];
    __shared__ float sx[MM1_NODES][N_FEAT + 1];
    int tid = threadIdx.x;
    int n0 = blockIdx.x * MM1_NODES;

    for (int i = tid; i < N_FEAT * HIDDEN; i += 256)
        sw[i >> 7][i & 127] = W1[i];
    if (tid < MM1_NODES * N_FEAT) {
        int n = tid >> 4, k = tid & 15;
        sx[n][k] = a[(n0 + n) * N_FEAT + k];
    }
    __syncthreads();

    int f = tid & 127, half = tid >> 7;
    float bias = b1[f];
    float acc[8] = {0,0,0,0,0,0,0,0};
    #pragma unroll
    for (int k = 0; k < N_FEAT; ++k) {
        float w = sw[k][f];
        #pragma unroll
        for (int i = 0; i < 8; ++i)
            acc[i] += sx[half * 8 + i][k] * w;
    }
    #pragma unroll
    for (int i = 0; i < 8; ++i)
        out[(n0 + half * 8 + i) * HIDDEN + f] =
            __float2bfloat16(fmaxf(acc[i] + bias, 0.0f));
}

// ---------------- layer-2 aggregation, bf16 gather -> bf16 output ----------------

__device__ __forceinline__ float bf_lo(unsigned u) {
    union { unsigned i; float f; } c; c.i = u << 16; return c.f;
}
__device__ __forceinline__ float bf_hi(unsigned u) {
    union { unsigned i; float f; } c; c.i = u & 0xffff0000u; return c.f;
}

__global__ __launch_bounds__(256) void k_agg2(const int* __restrict__ rowptr,
                                              const int* __restrict__ esrc,
                                              const float* __restrict__ dinv,
                                              const ushort_t* __restrict__ h1,
                                              ushort_t* __restrict__ aggb) {
    int tid = threadIdx.x;
    int sub = tid >> 5;      // 0..7 node within block
    int l32 = tid & 31;      // 8-byte lane within node row
    int node = blockIdx.x * 8 + sub;
    const uint2* h = (const uint2*)h1;   // row = 32 x uint2 (4 bf16 each)
    int beg = rowptr[node], end = rowptr[node + 1];
    float dd = dinv[node];
    uint2 sv = h[node * 32 + l32];
    float dd2 = dd * dd;
    float a0 = bf_lo(sv.x) * dd2, a1 = bf_hi(sv.x) * dd2;
    float a2 = bf_lo(sv.y) * dd2, a3 = bf_hi(sv.y) * dd2;

    int j = beg;
    for (; j + 4 <= end; j += 4) {
        int s0 = esrc[j], s1 = esrc[j + 1], s2 = esrc[j + 2], s3 = esrc[j + 3];
        float w0 = dinv[s0] * dd, w1 = dinv[s1] * dd,
              w2 = dinv[s2] * dd, w3 = dinv[s3] * dd;
        uint2 v0 = h[s0 * 32 + l32];
        uint2 v1 = h[s1 * 32 + l32];
        uint2 v2 = h[s2 * 32 + l32];
        uint2 v3 = h[s3 * 32 + l32];
        a0 += bf_lo(v0.x) * w0 + bf_lo(v1.x) * w1 + bf_lo(v2.x) * w2 + bf_lo(v3.x) * w3;
        a1 += bf_hi(v0.x) * w0 + bf_hi(v1.x) * w1 + bf_hi(v2.x) * w2 + bf_hi(v3.x) * w3;
        a2 += bf_lo(v0.y) * w0 + bf_lo(v1.y) * w1 + bf_lo(v2.y) * w2 + bf_lo(v3.y) * w3;
        a3 += bf_hi(v0.y) * w0 + bf_hi(v1.y) * w1 + bf_hi(v2.y) * w2 + bf_hi(v3.y) * w3;
    }
    for (; j < end; ++j) {
        int s = esrc[j];
        float w = dinv[s] * dd;
        uint2 v = h[s * 32 + l32];
        a0 += bf_lo(v.x) * w; a1 += bf_hi(v.x) * w;
        a2 += bf_lo(v.y) * w; a3 += bf_hi(v.y) * w;
    }
    ushort4 r;
    r.x = f2bf(a0); r.y = f2bf(a1); r.z = f2bf(a2); r.w = f2bf(a3);
    ((ushort4*)aggb)[node * 32 + l32] = r;
}

// ---------------- pack W2 -> bf16 MFMA B-fragment order ----------------
// B-frag for 16x16x32: lane holds B[k = quad*8+j][n = lane&15];
// Bp[((kt*8+nt)*64 + lane)*8 + j] = bf16(W2[kt*32 + quad*8 + j][nt*16 + (lane&15)])

__global__ void k_packB(const float* __restrict__ W2, ushort_t* __restrict__ Bp) {
    int idx = blockIdx.x * 256 + threadIdx.x;   // 0..16383
    int j = idx & 7;
    int lane = (idx >> 3) & 63;
    int nt = (idx >> 9) & 7;
    int kt = idx >> 12;
    int k = kt * 32 + (lane >> 4) * 8 + j;
    int n = nt * 16 + (lane & 15);
    Bp[idx] = f2bf(W2[k * HIDDEN + n]);
}

// ---------------- mm2 via MFMA, fused head ----------------
// block = 64 nodes (4 waves x 16); A-frags from global bf16; B staged in LDS.
// snode[n] = dot(relu(aggb[n]@W2 + b2), Wl)

__global__ __launch_bounds__(256) void k_mm2m(const ushort_t* __restrict__ A,
                                              const ushort_t* __restrict__ Bp,
                                              const float* __restrict__ b2,
                                              const float* __restrict__ Wl,
                                              float* __restrict__ snode) {
    __shared__ ushort_t sB[16384];   // 32 KB packed W2
    int tid = threadIdx.x;
    {
        const uint4* s = (const uint4*)Bp;
        uint4* d = (uint4*)sB;
        #pragma unroll
        for (int j = 0; j < 8; ++j) d[tid + 256 * j] = s[tid + 256 * j];
    }
    __syncthreads();

    int wv = tid >> 6, lane = tid & 63;
    int m = lane & 15, quad = lane >> 4;
    int node0 = blockIdx.x * 64 + wv * 16;
    const ushort_t* arow = A + (size_t)(node0 + m) * HIDDEN;

    v4f acc[8];
    #pragma unroll
    for (int nt = 0; nt < 8; ++nt) acc[nt] = (v4f){0.f, 0.f, 0.f, 0.f};

    #pragma unroll
    for (int kt = 0; kt < 4; ++kt) {
        v8s a = *(const v8s*)(arow + kt * 32 + quad * 8);
        #pragma unroll
        for (int nt = 0; nt < 8; ++nt) {
            v8s b = *(const v8s*)(&sB[((kt * 8 + nt) * 64 + lane) * 8]);
            acc[nt] = __builtin_amdgcn_mfma_f32_16x16x32_bf16(a, b, acc[nt], 0, 0, 0);
        }
    }

    // C layout: col = nt*16 + (lane&15), row(node offset) = quad*4 + reg
    float part[4] = {0, 0, 0, 0};
    #pragma unroll
    for (int nt = 0; nt < 8; ++nt) {
        float bb = b2[nt * 16 + m];
        float wl = Wl[nt * 16 + m];
        #pragma unroll
        for (int reg = 0; reg < 4; ++reg)
            part[reg] += fmaxf(acc[nt][reg] + bb, 0.0f) * wl;
    }
    #pragma unroll
    for (int reg = 0; reg < 4; ++reg) {
        float p = part[reg];
        p += __shfl_xor(p, 1, 64);
        p += __shfl_xor(p, 2, 64);
        p += __shfl_xor(p, 4, 64);
        p += __shfl_xor(p, 8, 64);
        int node = node0 + quad * 4 + reg;
        if (m == 0 && node < N_NODES) snode[node] = p;
    }
}

// ---------------- pooling: out[g] = mean(snode over graph g) + bl ----------------

__global__ __launch_bounds__(256) void k_pool(const float* __restrict__ snode,
                                              const int* __restrict__ batch,
                                              const float* __restrict__ bl,
                                              float* __restrict__ out) {
    int g = blockIdx.x;
    int tid = threadIdx.x;
    __shared__ float sred[4];

    int lo = 0, hi = N_NODES;
    while (lo < hi) { int mid = (lo + hi) >> 1; if (batch[mid] < g) lo = mid + 1; else hi = mid; }
    int start = lo;
    hi = N_NODES;
    while (lo < hi) { int mid = (lo + hi) >> 1; if (batch[mid] < g + 1) lo = mid + 1; else hi = mid; }
    int end = lo;

    float acc = 0.0f;
    for (int n = start + tid; n < end; n += 256) acc += snode[n];

    #pragma unroll
    for (int off = 32; off; off >>= 1) acc += __shfl_down(acc, off, 64);
    int wave = tid >> 6, lane = tid & 63;
    if (lane == 0) sred[wave] = acc;
    __syncthreads();
    if (tid == 0) {
        float s = sred[0] + sred[1] + sred[2] + sred[3];
        float cnt = (float)(end - start);
        out[g] = s / fmaxf(cnt, 1.0f) + bl[0];
    }
}

// ---------------- launch ----------------

extern "C" void kernel_launch(void* const* d_in, const int* in_sizes, int n_in,
                              void* d_out, int out_size, void* d_ws, size_t ws_size,
                              hipStream_t stream) {
    const float* x    = (const float*)d_in[0];
    const int*   src  = (const int*)d_in[1];
    const int*   dst  = src + N_EDGES;
    const int*   batch= (const int*)d_in[2];
    const float* W1   = (const float*)d_in[3];
    const float* b1   = (const float*)d_in[4];
    const float* W2   = (const float*)d_in[5];
    const float* b2   = (const float*)d_in[6];
    const float* Wl   = (const float*)d_in[7];
    const float* bl   = (const float*)d_in[8];
    float* out = (float*)d_out;

    const size_t NH = (size_t)N_NODES * HIDDEN;

    ushort_t* h1   = (ushort_t*)d_ws;          // NH bf16 (25.6 MB)
    ushort_t* aggb = h1 + NH;                  // NH bf16 (25.6 MB)
    float* agg16   = (float*)aggb;             // 6.4 MB, dead before aggb written
    float* dinv    = (float*)(aggb + NH);      // N_NODES
    float* snode   = dinv + N_NODES;           // N_NODES
    int*   cnt     = (int*)(snode + N_NODES);  // N_NODES
    int*   rowptr  = cnt + N_NODES;            // N_NODES+1
    int*   rank    = rowptr + N_NODES + 1;     // N_EDGES
    int*   bsum    = rank + N_EDGES;           // NB_SCAN
    int*   boff    = bsum + NB_SCAN;           // NB_SCAN
    int*   esrc    = boff + NB_SCAN;           // N_EDGES
    ushort_t* Bp   = (ushort_t*)(esrc + N_EDGES);  // 16384 (32 KB)

    // CSR build
    hipMemsetAsync(cnt, 0, N_NODES * sizeof(int), stream);
    k_deg<<<(N_EDGES + 255) / 256, 256, 0, stream>>>(dst, cnt, rank);
    k_bsum<<<NB_SCAN, 256, 0, stream>>>(cnt, bsum);
    k_scanb<<<1, 512, 0, stream>>>(bsum, boff);
    k_scanf<<<NB_SCAN, 256, 0, stream>>>(cnt, boff, rowptr, dinv);
    k_bucket<<<(N_EDGES + 255) / 256, 256, 0, stream>>>(src, dst, rank, rowptr, esrc);

    // pack W2 for MFMA
    k_packB<<<64, 256, 0, stream>>>(W2, Bp);

    // layer 1: aggregate in 16-dim, then matmul -> bf16 h1
    k_agg1<<<N_NODES / 4, 256, 0, stream>>>(rowptr, esrc, dinv, x, agg16);
    k_mm1b<<<N_NODES / MM1_NODES, 256, 0, stream>>>(agg16, W1, b1, (__hip_bfloat16*)h1);

    // layer 2: bf16 gather aggregate -> bf16, MFMA mm2 + fused head
    k_agg2<<<N_NODES / 8, 256, 0, stream>>>(rowptr, esrc, dinv, h1, aggb);
    k_mm2m<<<(N_NODES + 63) / 64, 256, 0, stream>>>(aggb, Bp, b2, Wl, snode);

    // pool + bias
    k_pool<<<N_GRAPHS, 256, 0, stream>>>(snode, batch, bl, out);
}